// Round 18
// baseline (128.397 us; speedup 1.0000x reference)
//
#include <hip/hip_runtime.h>
#include <hip/hip_fp16.h>
#include <math.h>

#define IN_DIM 128
#define HID 64
#define OUTD 32
#define BSH 8            // log2 nodes per bucket
#define BSZ 256          // nodes per bucket == threads per local-CSR block
#define EPB 4096         // edges per histogram/partition block
#define XPAD 136         // 128 + 8 fp16 pad
#define NCOPY 16         // spread copies of the stats accumulators

typedef __attribute__((ext_vector_type(8))) _Float16 f16x8;
typedef __attribute__((ext_vector_type(4))) float f32x4;

// Per-graph pointer bundle.
struct GB {
    const int* src; const int* dst;
    int* bh;               // [nbh][nb]: per-block bucket counts -> excl-in-bucket offsets
    int* btot;             // [nb] bucket totals (cross-bucket scan inlined where needed)
    unsigned int* pairs;   // bucket-partitioned edges: src | (local_dst << 24)
    int* rowptr; int* csr_src;
    float* dinv;
    double* st;            // [NCOPY][64] spread stats accumulators
    float* og;
    _Float16* o16;         // fp16 unnormalized output (pre z-score)
    const float* x;        // input features
    _Float16* hs;          // layer-1 matmul output; UNSCALED until local_csr, then *= dinv
    __half* h2;            // layer-2 matmul output, prescaled by dinv, fp16
};

// ---------------- stage 1: edge-bucket histogram (+1 block: W1^T fp16 pre-transpose) ----------------
__global__ void __launch_bounds__(256) k_hist(GB g0, GB g1, const float* __restrict__ W,
                                              _Float16* __restrict__ wt16, int e, int nb, int nbh) {
    int tid = threadIdx.x;
    int bx = blockIdx.x;
    if (bx == 2 * nbh) {
        // W1 [128][64] fp32 -> wt16 [64][128] fp16 (row d holds W^T[d][k])
        for (int i = tid; i < HID * IN_DIM; i += 256) {
            int d = i >> 7, k = i & 127;
            wt16[i] = (_Float16)W[k * HID + d];
        }
        return;
    }
    const GB& g = (bx >= nbh) ? g1 : g0;
    int blk = (bx >= nbh) ? bx - nbh : bx;
    __shared__ int hist[512];
    for (int i = tid; i < nb; i += 256) hist[i] = 0;
    __syncthreads();
    int base = blk * EPB;
#pragma unroll
    for (int k = 0; k < EPB / 256; ++k) {
        int idx = base + k * 256 + tid;
        if (idx < e) atomicAdd(&hist[g.dst[idx] >> BSH], 1);  // LDS atomic
    }
    __syncthreads();
    int* row = g.bh + (size_t)blk * nb;
    for (int i = tid; i < nb; i += 256) row[i] = hist[i];
}

// ---------------- stage 2: per-bucket column scan + zero stats copies ----------------
__global__ void k_colscan(GB g0, GB g1, int nb, int nbh) {
    const GB& g = blockIdx.y ? g1 : g0;
    __shared__ int ls[256];
    int tid = threadIdx.x;
    int b = blockIdx.x;
    int v = (tid < nbh) ? g.bh[(size_t)tid * nb + b] : 0;
    ls[tid] = v;
    __syncthreads();
    for (int off = 1; off < 256; off <<= 1) {
        int u = (tid >= off) ? ls[tid - off] : 0;
        __syncthreads();
        ls[tid] += u;
        __syncthreads();
    }
    if (tid < nbh) g.bh[(size_t)tid * nb + b] = ls[tid] - v;
    if (tid == 255) g.btot[b] = ls[255];
    if (b < 4) {  // zero the NCOPY*64 = 1024 stats doubles across 4 blocks
        int i = b * 256 + tid;
        g.st[i] = 0.0;
    }
}

// ---------------- stage 3 (fused): edge partition (XCD-partitioned) + layer-1 MFMA matmul ----------------
__global__ void __launch_bounds__(256) k_p2mm(GB g0, GB g1, const _Float16* __restrict__ wt16,
                                              int e, int n, int nb, int nbh, int slotsP, int nmm) {
    __shared__ char smem[2 * 64 * XPAD * 2];  // 34.8 KB union
    int tid = threadIdx.x;
    int bx = blockIdx.x;
    if (bx < slotsP) {
        // ---- partition role ----
        const GB& g = ((bx & 7) >= 4) ? g1 : g0;
        int blk = (bx >> 3) * 4 + (bx & 3);
        if (blk >= nbh) return;
        int* sc = (int*)smem;
        int* lcur = (int*)(smem + 1024);
        int v = (tid < nb) ? g.btot[tid] : 0;
        sc[tid] = v;
        __syncthreads();
        for (int off = 1; off < 256; off <<= 1) {
            int u = (tid >= off) ? sc[tid - off] : 0;
            __syncthreads();
            sc[tid] += u;
            __syncthreads();
        }
        int excl = sc[tid] - v;
        __syncthreads();
        sc[tid] = excl;   // sc now holds boff
        __syncthreads();
        const int* row = g.bh + (size_t)blk * nb;
        for (int i = tid; i < nb; i += 256) lcur[i] = sc[i] + row[i];
        __syncthreads();
        int base = blk * EPB;
#pragma unroll
        for (int k = 0; k < EPB / 256; ++k) {
            int idx = base + k * 256 + tid;
            if (idx < e) {
                int s = g.src[idx], d = g.dst[idx];
                int pos = atomicAdd(&lcur[d >> BSH], 1);          // LDS atomic
                g.pairs[pos] = (unsigned int)s | ((unsigned int)(d & (BSZ - 1)) << 24);
            }
        }
    } else {
        // ---- MFMA matmul role: hs[n,64](fp16) = X[n,128] @ W1[128,64] (unscaled) ----
        int mx = bx - slotsP;
        const GB& g = (mx >= nmm) ? g1 : g0;
        int blk = (mx >= nmm) ? mx - nmm : mx;
        _Float16 (*xs)[XPAD] = (_Float16(*)[XPAD])smem;
        _Float16 (*wt)[XPAD] = (_Float16(*)[XPAD])(smem + 64 * XPAD * 2);
        int node0 = blk * 64;
        {   // stage pre-transposed W1^T (fp16 [64][128]) into padded LDS: 1024 vector copies
            const f16x8* Wg = (const f16x8*)wt16;
#pragma unroll
            for (int j = 0; j < 4; ++j) {
                int i = tid + 256 * j;
                int d = i >> 4, koff = (i & 15) * 8;
                *(f16x8*)&wt[d][koff] = Wg[i];
            }
        }
        {   // stage X tile (fp32 -> fp16), coalesced float4 reads
            const float4* X4 = (const float4*)g.x;
#pragma unroll
            for (int j = 0; j < 8; ++j) {
                int i = tid + 256 * j;
                int row = i >> 5, c4 = i & 31;
                int gn = node0 + row;
                float4 v = (gn < n) ? X4[(size_t)gn * 32 + c4] : make_float4(0.f, 0.f, 0.f, 0.f);
                _Float16* p = &xs[row][c4 * 4];
                p[0] = (_Float16)v.x; p[1] = (_Float16)v.y;
                p[2] = (_Float16)v.z; p[3] = (_Float16)v.w;
            }
        }
        __syncthreads();
        int wv = tid >> 6, lane = tid & 63;
        int r16 = lane & 15, khi = lane >> 4;
        int wnode0 = wv * 16;
        f32x4 acc[4] = {};
#pragma unroll
        for (int kk = 0; kk < 4; ++kk) {
            f16x8 a = *(const f16x8*)&xs[wnode0 + r16][kk * 32 + khi * 8];
#pragma unroll
            for (int nt = 0; nt < 4; ++nt) {
                f16x8 b = *(const f16x8*)&wt[nt * 16 + r16][kk * 32 + khi * 8];
                acc[nt] = __builtin_amdgcn_mfma_f32_16x16x32_f16(a, b, acc[nt], 0, 0, 0);
            }
        }
#pragma unroll
        for (int r = 0; r < 4; ++r) {
            int node = node0 + wnode0 + khi * 4 + r;
            if (node < n) {
#pragma unroll
                for (int nt = 0; nt < 4; ++nt)
                    g.hs[(size_t)node * HID + nt * 16 + r16] = (_Float16)acc[nt][r];
            }
        }
    }
}

// ---------------- stage 4: per-bucket local CSR + hs prescale (XCD-partitioned; inline scan) ----------------
__global__ void __launch_bounds__(256) k_local_csr(GB g0, GB g1, int n, int e, int nb) {
    int bx = blockIdx.x;
    const GB& g = ((bx & 7) >= 4) ? g1 : g0;
    int b = (bx >> 3) * 4 + (bx & 3);
    if (b >= nb) return;
    __shared__ int sc[256], ldeg[BSZ], lrow[BSZ];
    __shared__ float ldv[BSZ];
    int tid = threadIdx.x;
    int v = (tid < nb) ? g.btot[tid] : 0;
    sc[tid] = v;
    __syncthreads();
    for (int off = 1; off < 256; off <<= 1) {
        int u = (tid >= off) ? sc[tid - off] : 0;
        __syncthreads();
        sc[tid] += u;
        __syncthreads();
    }
    int excl = sc[tid] - v;
    __syncthreads();
    sc[tid] = excl;
    __syncthreads();
    int node0 = b << BSH;
    int lo = sc[b], hi = lo + g.btot[b];
    ldeg[tid] = 0;
    __syncthreads();
    for (int j = lo + tid; j < hi; j += 256)
        atomicAdd(&ldeg[g.pairs[j] >> 24], 1);
    __syncthreads();
    int d = ldeg[tid];
    lrow[tid] = d;
    __syncthreads();
    for (int off = 1; off < BSZ; off <<= 1) {
        int u = (tid >= off) ? lrow[tid - off] : 0;
        __syncthreads();
        lrow[tid] += u;
        __syncthreads();
    }
    int node = node0 + tid;
    if (node < n) {
        g.rowptr[node] = lo + lrow[tid] - d;
        float dvv = rsqrtf((float)(d + 1));   // +1 = self-loop
        g.dinv[node] = dvv;
        ldv[tid] = dvv;
    } else {
        ldv[tid] = 0.0f;
    }
    lrow[tid] = lo + lrow[tid] - d;
    __syncthreads();
    for (int j = lo + tid; j < hi; j += 256) {
        unsigned int w = g.pairs[j];
        int pos = atomicAdd(&lrow[w >> 24], 1);  // LDS atomic
        g.csr_src[pos] = (int)(w & 0xFFFFFFu);
    }
    if (b == 0 && tid == 0) g.rowptr[n] = e;
    // prescale hs rows of this bucket: hs'[i] = dinv[i]*hs[i]  (coalesced half2)
    __half2* Hv = (__half2*)g.hs;
    for (int i = tid; i < BSZ * (HID / 2); i += 256) {
        int row = i >> 5;           // HID/2 == 32 half2 per row
        int nd = node0 + row;
        if (nd < n) {
            float scv = ldv[row];
            size_t idx = (size_t)nd * (HID / 2) + (i & 31);
            float2 vv = __half22float2(Hv[idx]);
            Hv[idx] = __floats2half2_rn(vv.x * scv, vv.y * scv);
        }
    }
}

// ---------------- layer-1 gather (XCD-partitioned; nt csr_src stream) + fused layer-2 matmul ----------------
__global__ void __launch_bounds__(256) k_gather_fuse(GB g0, GB g1, const float* __restrict__ b1,
                                                     const float* __restrict__ W2, int n, int nblkg) {
    int bx = blockIdx.x;
    const GB& g = ((bx & 7) >= 4) ? g1 : g0;
    int blk = (bx >> 3) * 4 + (bx & 3);
    if (blk >= nblkg) return;
    __shared__ float sh[32][HID + 1];  // +1 pad
    __shared__ float w2s[HID][OUTD];   // 8 KB
    __shared__ float bs[HID];
    int tid = threadIdx.x;
    for (int i = tid; i < HID * OUTD; i += 256) w2s[i >> 5][i & 31] = W2[i];
    if (tid < HID) bs[tid] = b1[tid];
    int l8 = tid & 7, gi = tid >> 3;   // 8 lanes/node, 32 nodes/block
    int node = blk * 32 + gi;
    float a[8] = {};
    if (node < n) {
        const f16x8* H = (const f16x8*)g.hs;  // row = 8 x f16x8 (prescaled by dinv[src])
        f16x8 v = H[(size_t)node * 8 + l8];   // self-loop
#pragma unroll
        for (int k = 0; k < 8; ++k) a[k] = (float)v[k];
        int lo = __builtin_nontemporal_load(&g.rowptr[node]);
        int hi = __builtin_nontemporal_load(&g.rowptr[node + 1]);
        int j = lo;
        for (; j + 8 <= hi; j += 8) {
            int s0 = __builtin_nontemporal_load(&g.csr_src[j]);
            int s1 = __builtin_nontemporal_load(&g.csr_src[j + 1]);
            int s2 = __builtin_nontemporal_load(&g.csr_src[j + 2]);
            int s3 = __builtin_nontemporal_load(&g.csr_src[j + 3]);
            int s4 = __builtin_nontemporal_load(&g.csr_src[j + 4]);
            int s5 = __builtin_nontemporal_load(&g.csr_src[j + 5]);
            int s6 = __builtin_nontemporal_load(&g.csr_src[j + 6]);
            int s7 = __builtin_nontemporal_load(&g.csr_src[j + 7]);
            f16x8 v0 = H[(size_t)s0 * 8 + l8];
            f16x8 v1 = H[(size_t)s1 * 8 + l8];
            f16x8 v2 = H[(size_t)s2 * 8 + l8];
            f16x8 v3 = H[(size_t)s3 * 8 + l8];
            f16x8 v4 = H[(size_t)s4 * 8 + l8];
            f16x8 v5 = H[(size_t)s5 * 8 + l8];
            f16x8 v6 = H[(size_t)s6 * 8 + l8];
            f16x8 v7 = H[(size_t)s7 * 8 + l8];
            f16x8 s01 = v0 + v1, s23 = v2 + v3, s45 = v4 + v5, s67 = v6 + v7;
            f16x8 s = (s01 + s23) + (s45 + s67);
#pragma unroll
            for (int k = 0; k < 8; ++k) a[k] += (float)s[k];
        }
        if (j + 4 <= hi) {
            int s0 = __builtin_nontemporal_load(&g.csr_src[j]);
            int s1 = __builtin_nontemporal_load(&g.csr_src[j + 1]);
            int s2 = __builtin_nontemporal_load(&g.csr_src[j + 2]);
            int s3 = __builtin_nontemporal_load(&g.csr_src[j + 3]);
            f16x8 v0 = H[(size_t)s0 * 8 + l8];
            f16x8 v1 = H[(size_t)s1 * 8 + l8];
            f16x8 v2 = H[(size_t)s2 * 8 + l8];
            f16x8 v3 = H[(size_t)s3 * 8 + l8];
            f16x8 s = (v0 + v1) + (v2 + v3);
#pragma unroll
            for (int k = 0; k < 8; ++k) a[k] += (float)s[k];
            j += 4;
        }
        for (; j < hi; ++j) {
            int s0 = __builtin_nontemporal_load(&g.csr_src[j]);
            f16x8 v0 = H[(size_t)s0 * 8 + l8];
#pragma unroll
            for (int k = 0; k < 8; ++k) a[k] += (float)v0[k];
        }
    }
    __syncthreads();  // bs/w2s ready; also orders sh writes below
    if (node < n) {
        float dv = g.dinv[node];
#pragma unroll
        for (int k = 0; k < 8; ++k)
            a[k] = fmaxf(fmaf(a[k], dv, bs[l8 * 8 + k]), 0.0f);
    }
#pragma unroll
    for (int k = 0; k < 8; ++k) sh[gi][l8 * 8 + k] = a[k];  // zeros for OOB nodes
    __syncthreads();
    // layer-2 matmul: 32 nodes x 32 fo; 4 outputs/thread; prescale by dinv
    int n2 = tid >> 3, fo = (tid & 7) * 4;
    int node2 = blk * 32 + n2;
    if (node2 < n) {
        float a0 = 0.f, a1 = 0.f, a2 = 0.f, a3 = 0.f;
#pragma unroll
        for (int k = 0; k < HID; ++k) {
            float s = sh[n2][k];
            a0 = fmaf(s, w2s[k][fo], a0);
            a1 = fmaf(s, w2s[k][fo + 1], a1);
            a2 = fmaf(s, w2s[k][fo + 2], a2);
            a3 = fmaf(s, w2s[k][fo + 3], a3);
        }
        float dv2 = g.dinv[node2];
        __half2* H2 = (__half2*)g.h2;
        H2[(size_t)node2 * (OUTD / 2) + (fo >> 1)]     = __floats2half2_rn(a0 * dv2, a1 * dv2);
        H2[(size_t)node2 * (OUTD / 2) + (fo >> 1) + 1] = __floats2half2_rn(a2 * dv2, a3 * dv2);
    }
}

// ---------------- layer-2 gather (XCD-partitioned; nt stream) + fused column stats; writes fp16 o16 ----------------
__global__ void __launch_bounds__(256) k_gather2s(GB g0, GB g1, int n, int nblkg) {
    int bx = blockIdx.x;
    const GB& g = ((bx & 7) >= 4) ? g1 : g0;
    int blk = (bx >> 3) * 4 + (bx & 3);
    if (blk >= nblkg) return;
    __shared__ float sx[64][33], sq[64][33];  // padded
    int tid = threadIdx.x;
    int l4 = tid & 3, gi = tid >> 2;   // 4 lanes/node, 64 nodes/block
    int node = blk * 64 + gi;
    float a[8] = {};
    if (node < n) {
        const f16x8* H = (const f16x8*)g.h2;  // row = 4 x f16x8 (prescaled)
        f16x8 v = H[(size_t)node * 4 + l4];   // self-loop
#pragma unroll
        for (int k = 0; k < 8; ++k) a[k] = (float)v[k];
        int lo = __builtin_nontemporal_load(&g.rowptr[node]);
        int hi = __builtin_nontemporal_load(&g.rowptr[node + 1]);
        int j = lo;
        for (; j + 8 <= hi; j += 8) {
            int s0 = __builtin_nontemporal_load(&g.csr_src[j]);
            int s1 = __builtin_nontemporal_load(&g.csr_src[j + 1]);
            int s2 = __builtin_nontemporal_load(&g.csr_src[j + 2]);
            int s3 = __builtin_nontemporal_load(&g.csr_src[j + 3]);
            int s4 = __builtin_nontemporal_load(&g.csr_src[j + 4]);
            int s5 = __builtin_nontemporal_load(&g.csr_src[j + 5]);
            int s6 = __builtin_nontemporal_load(&g.csr_src[j + 6]);
            int s7 = __builtin_nontemporal_load(&g.csr_src[j + 7]);
            f16x8 v0 = H[(size_t)s0 * 4 + l4];
            f16x8 v1 = H[(size_t)s1 * 4 + l4];
            f16x8 v2 = H[(size_t)s2 * 4 + l4];
            f16x8 v3 = H[(size_t)s3 * 4 + l4];
            f16x8 v4 = H[(size_t)s4 * 4 + l4];
            f16x8 v5 = H[(size_t)s5 * 4 + l4];
            f16x8 v6 = H[(size_t)s6 * 4 + l4];
            f16x8 v7 = H[(size_t)s7 * 4 + l4];
            f16x8 s01 = v0 + v1, s23 = v2 + v3, s45 = v4 + v5, s67 = v6 + v7;
            f16x8 s = (s01 + s23) + (s45 + s67);
#pragma unroll
            for (int k = 0; k < 8; ++k) a[k] += (float)s[k];
        }
        if (j + 4 <= hi) {
            int s0 = __builtin_nontemporal_load(&g.csr_src[j]);
            int s1 = __builtin_nontemporal_load(&g.csr_src[j + 1]);
            int s2 = __builtin_nontemporal_load(&g.csr_src[j + 2]);
            int s3 = __builtin_nontemporal_load(&g.csr_src[j + 3]);
            f16x8 v0 = H[(size_t)s0 * 4 + l4];
            f16x8 v1 = H[(size_t)s1 * 4 + l4];
            f16x8 v2 = H[(size_t)s2 * 4 + l4];
            f16x8 v3 = H[(size_t)s3 * 4 + l4];
            f16x8 s = (v0 + v1) + (v2 + v3);
#pragma unroll
            for (int k = 0; k < 8; ++k) a[k] += (float)s[k];
            j += 4;
        }
        for (; j < hi; ++j) {
            int s0 = __builtin_nontemporal_load(&g.csr_src[j]);
            f16x8 v0 = H[(size_t)s0 * 4 + l4];
#pragma unroll
            for (int k = 0; k < 8; ++k) a[k] += (float)v0[k];
        }
        float dv = g.dinv[node];
#pragma unroll
        for (int k = 0; k < 8; ++k) a[k] *= dv;
        f16x8 o;
#pragma unroll
        for (int k = 0; k < 8; ++k) o[k] = (_Float16)a[k];
        ((f16x8*)g.o16)[(size_t)node * 4 + l4] = o;   // 16B store
    }
    // column partial sums (zeros for OOB threads)
#pragma unroll
    for (int k = 0; k < 8; ++k) {
        sx[gi][l4 * 8 + k] = a[k];
        sq[gi][l4 * 8 + k] = a[k] * a[k];
    }
    __syncthreads();
    if (tid < 64) {
        int c = tid & 31;
        bool isq = tid >= 32;
        float s = 0.0f;
        for (int r = 0; r < 64; ++r) s += isq ? sq[r][c] : sx[r][c];
        atomicAdd(&g.st[(blk & (NCOPY - 1)) * 64 + c + (isq ? 32 : 0)], (double)s);
    }
}

// ---------------- transform: finalize stats + normalize o16 -> og (fp32), 4 elems/thread ----------------
__global__ void k_transform(GB g0, GB g1, int n) {
    const GB& g = blockIdx.y ? g1 : g0;
    __shared__ float fm[32], fr[32];
    int tid = threadIdx.x;
    if (tid < 32) {
        double sum = 0.0, sqs = 0.0;
#pragma unroll
        for (int k = 0; k < NCOPY; ++k) {
            sum += g.st[k * 64 + tid];
            sqs += g.st[k * 64 + tid + 32];
        }
        double mean = sum / (double)n;
        double var = (sqs - sum * sum / (double)n) / (double)(n - 1);
        fm[tid] = (float)mean;
        fr[tid] = (float)(1.0 / sqrt(var));
    }
    __syncthreads();
    int t4 = (blockIdx.x * 256 + tid) * 4;
    if (t4 < n * OUTD) {
        const __half2* O = (const __half2*)g.o16;
        float2 u0 = __half22float2(O[t4 / 2]);
        float2 u1 = __half22float2(O[t4 / 2 + 1]);
        int c = t4 & 31;
        float4 r;
        r.x = (u0.x - fm[c])     * fr[c];
        r.y = (u0.y - fm[c + 1]) * fr[c + 1];
        r.z = (u1.x - fm[c + 2]) * fr[c + 2];
        r.w = (u1.y - fm[c + 3]) * fr[c + 3];
        *(float4*)&g.og[t4] = r;
    }
}

// ---------------- launch ----------------

extern "C" void kernel_launch(void* const* d_in, const int* in_sizes, int n_in,
                              void* d_out, int out_size, void* d_ws, size_t ws_size,
                              hipStream_t stream) {
    const float* x1 = (const float*)d_in[0];
    const int*   ei1 = (const int*)d_in[1];
    const float* x2 = (const float*)d_in[2];
    const int*   ei2 = (const int*)d_in[3];
    const float* W1 = (const float*)d_in[4];
    const float* b1 = (const float*)d_in[5];
    const float* W2 = (const float*)d_in[6];
    const float* b2 = (const float*)d_in[7];
    (void)b2;  // column-constant shift cancels exactly in the z-score
    (void)n_in; (void)out_size; (void)ws_size;

    int n = in_sizes[0] / IN_DIM;    // 50000
    int e = in_sizes[1] / 2;         // 800000
    float* out = (float*)d_out;
    int nb  = (n + BSZ - 1) >> BSH;  // 196 buckets (must be <= 256 for inline scans)
    int nbh = (e + EPB - 1) / EPB;   // 196 edge blocks (must be <= 256)
    int nmm = (n + 63) / 64;         // 782 matmul blocks

    char* ws = (char*)d_ws;
    size_t off = 0;
    auto alloc = [&](size_t bytes) {
        void* p = ws + off;
        off = (off + bytes + 255) & ~(size_t)255;
        return p;
    };
    int*    bh_base   = (int*)alloc((size_t)2 * nbh * nb * 4);
    int*    btot_base = (int*)alloc((size_t)2 * nb * 4);
    double* st_base   = (double*)alloc((size_t)2 * NCOPY * 64 * 8);
    _Float16* o16_base = (_Float16*)alloc((size_t)2 * n * OUTD * 2);
    _Float16* wt16     = (_Float16*)alloc((size_t)HID * IN_DIM * 2);  // W1^T fp16

    GB G[2];
    for (int g = 0; g < 2; ++g) {
        const int* ei = g ? ei2 : ei1;
        G[g].src  = ei;
        G[g].dst  = ei + e;
        G[g].x    = g ? x2 : x1;
        G[g].bh   = bh_base + (size_t)g * nbh * nb;
        G[g].btot = btot_base + (size_t)g * nb;
        G[g].st   = st_base + (size_t)g * NCOPY * 64;
        G[g].o16  = o16_base + (size_t)g * n * OUTD;
        G[g].rowptr  = (int*)alloc(((size_t)n + 1) * 4);
        G[g].csr_src = (int*)alloc((size_t)e * 4);
        G[g].dinv    = (float*)alloc((size_t)n * 4);
        G[g].og      = out + (size_t)g * n * OUTD;
        G[g].hs      = (_Float16*)alloc((size_t)n * HID * 2);  // live from p2mm on
    }
    // pairs (dead after local_csr) aliases h2 buffers (live from gather_fuse on)
    size_t pairs_bytes = (size_t)2 * e * 4;
    size_t h2_bytes    = (size_t)2 * n * OUTD * 2;
    char* uni = (char*)alloc(pairs_bytes > h2_bytes ? pairs_bytes : h2_bytes);
    G[0].pairs = (unsigned int*)uni;
    G[1].pairs = G[0].pairs + e;
    G[0].h2 = (__half*)uni;
    G[1].h2 = G[0].h2 + (size_t)n * OUTD;

    // stage 1: histogram both graphs (+1 block W1^T prep)
    k_hist<<<dim3(2 * nbh + 1), 256, 0, stream>>>(G[0], G[1], W1, wt16, e, nb, nbh);
    // stage 2: per-bucket column scans (both graphs via y)
    k_colscan<<<dim3(nb, 2), 256, 0, stream>>>(G[0], G[1], nb, nbh);
    // stage 3: partition (XCD-partitioned) + MFMA matmul fused in one launch
    int slotsP = ((nbh + 3) / 4) * 8;
    k_p2mm<<<dim3(slotsP + 2 * nmm), 256, 0, stream>>>(G[0], G[1], wt16, e, n, nb, nbh, slotsP, nmm);
    // stage 4: local CSR + prescale (XCD-partitioned)
    int slotsC = ((nb + 3) / 4) * 8;
    k_local_csr<<<dim3(slotsC), BSZ, 0, stream>>>(G[0], G[1], n, e, nb);

    // gathers, XCD-partitioned by graph (slots 0-3 -> g0, 4-7 -> g1)
    int nblkg1 = (n + 31) / 32;
    int slots1 = ((nblkg1 + 3) / 4) * 8;
    k_gather_fuse<<<dim3(slots1), 256, 0, stream>>>(G[0], G[1], b1, W2, n, nblkg1);
    int nblkg2 = (n + 63) / 64;
    int slots2 = ((nblkg2 + 3) / 4) * 8;
    k_gather2s<<<dim3(slots2), 256, 0, stream>>>(G[0], G[1], n, nblkg2);

    // z-score transform (finalize folded; st zeroed in k_colscan)
    k_transform<<<dim3((n * OUTD / 4 + 255) / 256, 2), 256, 0, stream>>>(G[0], G[1], n);
}

// Round 19
// 119.069 us; speedup vs baseline: 1.0783x; 1.0783x over previous
//
#include <hip/hip_runtime.h>
#include <hip/hip_fp16.h>
#include <math.h>

#define IN_DIM 128
#define HID 64
#define OUTD 32
#define BSH 8            // log2 nodes per bucket
#define BSZ 256          // nodes per bucket == threads per local-CSR block
#define EPB 4096         // edges per histogram/partition block
#define XPAD 136         // 128 + 8 fp16 pad
#define NCOPY 16         // spread copies of the stats accumulators

typedef __attribute__((ext_vector_type(8))) _Float16 f16x8;
typedef __attribute__((ext_vector_type(4))) float f32x4;

// Per-graph pointer bundle.
struct GB {
    const int* src; const int* dst;
    int* bh;               // [nbh][nb]: per-block bucket counts -> excl-in-bucket offsets
    int* btot;             // [nb] bucket totals (cross-bucket scan inlined where needed)
    unsigned int* pairs;   // bucket-partitioned edges: src | (local_dst << 24)
    int* rowptr; int* csr_src;
    float* dinv;
    double* st;            // [NCOPY][64] spread stats accumulators
    float* og;
    _Float16* o16;         // fp16 unnormalized output (pre z-score)
    const float* x;        // input features
    _Float16* hs;          // layer-1 matmul output; UNSCALED until local_csr, then *= dinv
    __half* h2;            // layer-2 matmul output, prescaled by dinv, fp16
};

// ---------------- stage 1: edge-bucket histogram (+1 block: W1^T fp16 pre-transpose) ----------------
__global__ void __launch_bounds__(256) k_hist(GB g0, GB g1, const float* __restrict__ W,
                                              _Float16* __restrict__ wt16, int e, int nb, int nbh) {
    int tid = threadIdx.x;
    int bx = blockIdx.x;
    if (bx == 2 * nbh) {
        // W1 [128][64] fp32 -> wt16 [64][128] fp16 (row d holds W^T[d][k])
        for (int i = tid; i < HID * IN_DIM; i += 256) {
            int d = i >> 7, k = i & 127;
            wt16[i] = (_Float16)W[k * HID + d];
        }
        return;
    }
    const GB& g = (bx >= nbh) ? g1 : g0;
    int blk = (bx >= nbh) ? bx - nbh : bx;
    __shared__ int hist[512];
    for (int i = tid; i < nb; i += 256) hist[i] = 0;
    __syncthreads();
    int base = blk * EPB;
#pragma unroll
    for (int k = 0; k < EPB / 256; ++k) {
        int idx = base + k * 256 + tid;
        if (idx < e) atomicAdd(&hist[g.dst[idx] >> BSH], 1);  // LDS atomic
    }
    __syncthreads();
    int* row = g.bh + (size_t)blk * nb;
    for (int i = tid; i < nb; i += 256) row[i] = hist[i];
}

// ---------------- stage 2: per-bucket column scan + zero stats copies ----------------
__global__ void k_colscan(GB g0, GB g1, int nb, int nbh) {
    const GB& g = blockIdx.y ? g1 : g0;
    __shared__ int ls[256];
    int tid = threadIdx.x;
    int b = blockIdx.x;
    int v = (tid < nbh) ? g.bh[(size_t)tid * nb + b] : 0;
    ls[tid] = v;
    __syncthreads();
    for (int off = 1; off < 256; off <<= 1) {
        int u = (tid >= off) ? ls[tid - off] : 0;
        __syncthreads();
        ls[tid] += u;
        __syncthreads();
    }
    if (tid < nbh) g.bh[(size_t)tid * nb + b] = ls[tid] - v;
    if (tid == 255) g.btot[b] = ls[255];
    if (b < 4) {  // zero the NCOPY*64 = 1024 stats doubles across 4 blocks
        int i = b * 256 + tid;
        g.st[i] = 0.0;
    }
}

// ---------------- stage 3 (fused): edge partition (XCD-partitioned) + layer-1 MFMA matmul ----------------
__global__ void __launch_bounds__(256) k_p2mm(GB g0, GB g1, const _Float16* __restrict__ wt16,
                                              int e, int n, int nb, int nbh, int slotsP, int nmm) {
    __shared__ char smem[2 * 64 * XPAD * 2];  // 34.8 KB union
    int tid = threadIdx.x;
    int bx = blockIdx.x;
    if (bx < slotsP) {
        // ---- partition role ----
        const GB& g = ((bx & 7) >= 4) ? g1 : g0;
        int blk = (bx >> 3) * 4 + (bx & 3);
        if (blk >= nbh) return;
        int* sc = (int*)smem;
        int* lcur = (int*)(smem + 1024);
        int v = (tid < nb) ? g.btot[tid] : 0;
        sc[tid] = v;
        __syncthreads();
        for (int off = 1; off < 256; off <<= 1) {
            int u = (tid >= off) ? sc[tid - off] : 0;
            __syncthreads();
            sc[tid] += u;
            __syncthreads();
        }
        int excl = sc[tid] - v;
        __syncthreads();
        sc[tid] = excl;   // sc now holds boff
        __syncthreads();
        const int* row = g.bh + (size_t)blk * nb;
        for (int i = tid; i < nb; i += 256) lcur[i] = sc[i] + row[i];
        __syncthreads();
        int base = blk * EPB;
#pragma unroll
        for (int k = 0; k < EPB / 256; ++k) {
            int idx = base + k * 256 + tid;
            if (idx < e) {
                int s = g.src[idx], d = g.dst[idx];
                int pos = atomicAdd(&lcur[d >> BSH], 1);          // LDS atomic
                g.pairs[pos] = (unsigned int)s | ((unsigned int)(d & (BSZ - 1)) << 24);
            }
        }
    } else {
        // ---- MFMA matmul role: hs[n,64](fp16) = X[n,128] @ W1[128,64] (unscaled) ----
        int mx = bx - slotsP;
        const GB& g = (mx >= nmm) ? g1 : g0;
        int blk = (mx >= nmm) ? mx - nmm : mx;
        _Float16 (*xs)[XPAD] = (_Float16(*)[XPAD])smem;
        _Float16 (*wt)[XPAD] = (_Float16(*)[XPAD])(smem + 64 * XPAD * 2);
        int node0 = blk * 64;
        {   // stage pre-transposed W1^T (fp16 [64][128]) into padded LDS: 1024 vector copies
            const f16x8* Wg = (const f16x8*)wt16;
#pragma unroll
            for (int j = 0; j < 4; ++j) {
                int i = tid + 256 * j;
                int d = i >> 4, koff = (i & 15) * 8;
                *(f16x8*)&wt[d][koff] = Wg[i];
            }
        }
        {   // stage X tile (fp32 -> fp16), coalesced float4 reads
            const float4* X4 = (const float4*)g.x;
#pragma unroll
            for (int j = 0; j < 8; ++j) {
                int i = tid + 256 * j;
                int row = i >> 5, c4 = i & 31;
                int gn = node0 + row;
                float4 v = (gn < n) ? X4[(size_t)gn * 32 + c4] : make_float4(0.f, 0.f, 0.f, 0.f);
                _Float16* p = &xs[row][c4 * 4];
                p[0] = (_Float16)v.x; p[1] = (_Float16)v.y;
                p[2] = (_Float16)v.z; p[3] = (_Float16)v.w;
            }
        }
        __syncthreads();
        int wv = tid >> 6, lane = tid & 63;
        int r16 = lane & 15, khi = lane >> 4;
        int wnode0 = wv * 16;
        f32x4 acc[4] = {};
#pragma unroll
        for (int kk = 0; kk < 4; ++kk) {
            f16x8 a = *(const f16x8*)&xs[wnode0 + r16][kk * 32 + khi * 8];
#pragma unroll
            for (int nt = 0; nt < 4; ++nt) {
                f16x8 b = *(const f16x8*)&wt[nt * 16 + r16][kk * 32 + khi * 8];
                acc[nt] = __builtin_amdgcn_mfma_f32_16x16x32_f16(a, b, acc[nt], 0, 0, 0);
            }
        }
#pragma unroll
        for (int r = 0; r < 4; ++r) {
            int node = node0 + wnode0 + khi * 4 + r;
            if (node < n) {
#pragma unroll
                for (int nt = 0; nt < 4; ++nt)
                    g.hs[(size_t)node * HID + nt * 16 + r16] = (_Float16)acc[nt][r];
            }
        }
    }
}

// ---------------- stage 4: per-bucket local CSR + hs prescale (XCD-partitioned; inline scan) ----------------
__global__ void __launch_bounds__(256) k_local_csr(GB g0, GB g1, int n, int e, int nb) {
    int bx = blockIdx.x;
    const GB& g = ((bx & 7) >= 4) ? g1 : g0;
    int b = (bx >> 3) * 4 + (bx & 3);
    if (b >= nb) return;
    __shared__ int sc[256], ldeg[BSZ], lrow[BSZ];
    __shared__ float ldv[BSZ];
    int tid = threadIdx.x;
    int v = (tid < nb) ? g.btot[tid] : 0;
    sc[tid] = v;
    __syncthreads();
    for (int off = 1; off < 256; off <<= 1) {
        int u = (tid >= off) ? sc[tid - off] : 0;
        __syncthreads();
        sc[tid] += u;
        __syncthreads();
    }
    int excl = sc[tid] - v;
    __syncthreads();
    sc[tid] = excl;
    __syncthreads();
    int node0 = b << BSH;
    int lo = sc[b], hi = lo + g.btot[b];
    ldeg[tid] = 0;
    __syncthreads();
    for (int j = lo + tid; j < hi; j += 256)
        atomicAdd(&ldeg[g.pairs[j] >> 24], 1);
    __syncthreads();
    int d = ldeg[tid];
    lrow[tid] = d;
    __syncthreads();
    for (int off = 1; off < BSZ; off <<= 1) {
        int u = (tid >= off) ? lrow[tid - off] : 0;
        __syncthreads();
        lrow[tid] += u;
        __syncthreads();
    }
    int node = node0 + tid;
    if (node < n) {
        g.rowptr[node] = lo + lrow[tid] - d;
        float dvv = rsqrtf((float)(d + 1));   // +1 = self-loop
        g.dinv[node] = dvv;
        ldv[tid] = dvv;
    } else {
        ldv[tid] = 0.0f;
    }
    lrow[tid] = lo + lrow[tid] - d;
    __syncthreads();
    for (int j = lo + tid; j < hi; j += 256) {
        unsigned int w = g.pairs[j];
        int pos = atomicAdd(&lrow[w >> 24], 1);  // LDS atomic
        g.csr_src[pos] = (int)(w & 0xFFFFFFu);
    }
    if (b == 0 && tid == 0) g.rowptr[n] = e;
    // prescale hs rows of this bucket: hs'[i] = dinv[i]*hs[i]  (coalesced half2)
    __half2* Hv = (__half2*)g.hs;
    for (int i = tid; i < BSZ * (HID / 2); i += 256) {
        int row = i >> 5;           // HID/2 == 32 half2 per row
        int nd = node0 + row;
        if (nd < n) {
            float scv = ldv[row];
            size_t idx = (size_t)nd * (HID / 2) + (i & 31);
            float2 vv = __half22float2(Hv[idx]);
            Hv[idx] = __floats2half2_rn(vv.x * scv, vv.y * scv);
        }
    }
}

// ---------------- layer-1 gather (XCD-partitioned by graph) + fused layer-2 matmul ----------------
__global__ void __launch_bounds__(256) k_gather_fuse(GB g0, GB g1, const float* __restrict__ b1,
                                                     const float* __restrict__ W2, int n, int nblkg) {
    int bx = blockIdx.x;
    const GB& g = ((bx & 7) >= 4) ? g1 : g0;
    int blk = (bx >> 3) * 4 + (bx & 3);
    if (blk >= nblkg) return;
    __shared__ float sh[32][HID + 1];  // +1 pad
    __shared__ float w2s[HID][OUTD];   // 8 KB
    __shared__ float bs[HID];
    int tid = threadIdx.x;
    for (int i = tid; i < HID * OUTD; i += 256) w2s[i >> 5][i & 31] = W2[i];
    if (tid < HID) bs[tid] = b1[tid];
    int l8 = tid & 7, gi = tid >> 3;   // 8 lanes/node, 32 nodes/block
    int node = blk * 32 + gi;
    float a[8] = {};
    if (node < n) {
        const f16x8* H = (const f16x8*)g.hs;  // row = 8 x f16x8 (prescaled by dinv[src])
        f16x8 v = H[(size_t)node * 8 + l8];   // self-loop
#pragma unroll
        for (int k = 0; k < 8; ++k) a[k] = (float)v[k];
        int lo = g.rowptr[node], hi = g.rowptr[node + 1];
        int j = lo;
        for (; j + 8 <= hi; j += 8) {
            int s0 = g.csr_src[j],     s1 = g.csr_src[j + 1];
            int s2 = g.csr_src[j + 2], s3 = g.csr_src[j + 3];
            int s4 = g.csr_src[j + 4], s5 = g.csr_src[j + 5];
            int s6 = g.csr_src[j + 6], s7 = g.csr_src[j + 7];
            f16x8 v0 = H[(size_t)s0 * 8 + l8];
            f16x8 v1 = H[(size_t)s1 * 8 + l8];
            f16x8 v2 = H[(size_t)s2 * 8 + l8];
            f16x8 v3 = H[(size_t)s3 * 8 + l8];
            f16x8 v4 = H[(size_t)s4 * 8 + l8];
            f16x8 v5 = H[(size_t)s5 * 8 + l8];
            f16x8 v6 = H[(size_t)s6 * 8 + l8];
            f16x8 v7 = H[(size_t)s7 * 8 + l8];
            f16x8 s01 = v0 + v1, s23 = v2 + v3, s45 = v4 + v5, s67 = v6 + v7;
            f16x8 s = (s01 + s23) + (s45 + s67);
#pragma unroll
            for (int k = 0; k < 8; ++k) a[k] += (float)s[k];
        }
        if (j + 4 <= hi) {
            int s0 = g.csr_src[j],     s1 = g.csr_src[j + 1];
            int s2 = g.csr_src[j + 2], s3 = g.csr_src[j + 3];
            f16x8 v0 = H[(size_t)s0 * 8 + l8];
            f16x8 v1 = H[(size_t)s1 * 8 + l8];
            f16x8 v2 = H[(size_t)s2 * 8 + l8];
            f16x8 v3 = H[(size_t)s3 * 8 + l8];
            f16x8 s = (v0 + v1) + (v2 + v3);
#pragma unroll
            for (int k = 0; k < 8; ++k) a[k] += (float)s[k];
            j += 4;
        }
        for (; j < hi; ++j) {
            f16x8 v0 = H[(size_t)g.csr_src[j] * 8 + l8];
#pragma unroll
            for (int k = 0; k < 8; ++k) a[k] += (float)v0[k];
        }
    }
    __syncthreads();  // bs/w2s ready; also orders sh writes below
    if (node < n) {
        float dv = g.dinv[node];
#pragma unroll
        for (int k = 0; k < 8; ++k)
            a[k] = fmaxf(fmaf(a[k], dv, bs[l8 * 8 + k]), 0.0f);
    }
#pragma unroll
    for (int k = 0; k < 8; ++k) sh[gi][l8 * 8 + k] = a[k];  // zeros for OOB nodes
    __syncthreads();
    // layer-2 matmul: 32 nodes x 32 fo; 4 outputs/thread; prescale by dinv
    int n2 = tid >> 3, fo = (tid & 7) * 4;
    int node2 = blk * 32 + n2;
    if (node2 < n) {
        float a0 = 0.f, a1 = 0.f, a2 = 0.f, a3 = 0.f;
#pragma unroll
        for (int k = 0; k < HID; ++k) {
            float s = sh[n2][k];
            a0 = fmaf(s, w2s[k][fo], a0);
            a1 = fmaf(s, w2s[k][fo + 1], a1);
            a2 = fmaf(s, w2s[k][fo + 2], a2);
            a3 = fmaf(s, w2s[k][fo + 3], a3);
        }
        float dv2 = g.dinv[node2];
        __half2* H2 = (__half2*)g.h2;
        H2[(size_t)node2 * (OUTD / 2) + (fo >> 1)]     = __floats2half2_rn(a0 * dv2, a1 * dv2);
        H2[(size_t)node2 * (OUTD / 2) + (fo >> 1) + 1] = __floats2half2_rn(a2 * dv2, a3 * dv2);
    }
}

// ---------------- layer-2 gather (XCD-partitioned) + fused column stats; writes fp16 o16 ----------------
__global__ void __launch_bounds__(256) k_gather2s(GB g0, GB g1, int n, int nblkg) {
    int bx = blockIdx.x;
    const GB& g = ((bx & 7) >= 4) ? g1 : g0;
    int blk = (bx >> 3) * 4 + (bx & 3);
    if (blk >= nblkg) return;
    __shared__ float sx[64][33], sq[64][33];  // padded
    int tid = threadIdx.x;
    int l4 = tid & 3, gi = tid >> 2;   // 4 lanes/node, 64 nodes/block
    int node = blk * 64 + gi;
    float a[8] = {};
    if (node < n) {
        const f16x8* H = (const f16x8*)g.h2;  // row = 4 x f16x8 (prescaled)
        f16x8 v = H[(size_t)node * 4 + l4];   // self-loop
#pragma unroll
        for (int k = 0; k < 8; ++k) a[k] = (float)v[k];
        int lo = g.rowptr[node], hi = g.rowptr[node + 1];
        int j = lo;
        for (; j + 8 <= hi; j += 8) {
            int s0 = g.csr_src[j],     s1 = g.csr_src[j + 1];
            int s2 = g.csr_src[j + 2], s3 = g.csr_src[j + 3];
            int s4 = g.csr_src[j + 4], s5 = g.csr_src[j + 5];
            int s6 = g.csr_src[j + 6], s7 = g.csr_src[j + 7];
            f16x8 v0 = H[(size_t)s0 * 4 + l4];
            f16x8 v1 = H[(size_t)s1 * 4 + l4];
            f16x8 v2 = H[(size_t)s2 * 4 + l4];
            f16x8 v3 = H[(size_t)s3 * 4 + l4];
            f16x8 v4 = H[(size_t)s4 * 4 + l4];
            f16x8 v5 = H[(size_t)s5 * 4 + l4];
            f16x8 v6 = H[(size_t)s6 * 4 + l4];
            f16x8 v7 = H[(size_t)s7 * 4 + l4];
            f16x8 s01 = v0 + v1, s23 = v2 + v3, s45 = v4 + v5, s67 = v6 + v7;
            f16x8 s = (s01 + s23) + (s45 + s67);
#pragma unroll
            for (int k = 0; k < 8; ++k) a[k] += (float)s[k];
        }
        if (j + 4 <= hi) {
            int s0 = g.csr_src[j],     s1 = g.csr_src[j + 1];
            int s2 = g.csr_src[j + 2], s3 = g.csr_src[j + 3];
            f16x8 v0 = H[(size_t)s0 * 4 + l4];
            f16x8 v1 = H[(size_t)s1 * 4 + l4];
            f16x8 v2 = H[(size_t)s2 * 4 + l4];
            f16x8 v3 = H[(size_t)s3 * 4 + l4];
            f16x8 s = (v0 + v1) + (v2 + v3);
#pragma unroll
            for (int k = 0; k < 8; ++k) a[k] += (float)s[k];
            j += 4;
        }
        for (; j < hi; ++j) {
            f16x8 v0 = H[(size_t)g.csr_src[j] * 4 + l4];
#pragma unroll
            for (int k = 0; k < 8; ++k) a[k] += (float)v0[k];
        }
        float dv = g.dinv[node];
#pragma unroll
        for (int k = 0; k < 8; ++k) a[k] *= dv;
        f16x8 o;
#pragma unroll
        for (int k = 0; k < 8; ++k) o[k] = (_Float16)a[k];
        ((f16x8*)g.o16)[(size_t)node * 4 + l4] = o;   // 16B store
    }
    // column partial sums (zeros for OOB threads)
#pragma unroll
    for (int k = 0; k < 8; ++k) {
        sx[gi][l4 * 8 + k] = a[k];
        sq[gi][l4 * 8 + k] = a[k] * a[k];
    }
    __syncthreads();
    if (tid < 64) {
        int c = tid & 31;
        bool isq = tid >= 32;
        float s = 0.0f;
        for (int r = 0; r < 64; ++r) s += isq ? sq[r][c] : sx[r][c];
        atomicAdd(&g.st[(blk & (NCOPY - 1)) * 64 + c + (isq ? 32 : 0)], (double)s);
    }
}

// ---------------- transform: finalize stats + normalize o16 -> og (fp32), 4 elems/thread ----------------
__global__ void k_transform(GB g0, GB g1, int n) {
    const GB& g = blockIdx.y ? g1 : g0;
    __shared__ float fm[32], fr[32];
    int tid = threadIdx.x;
    if (tid < 32) {
        double sum = 0.0, sqs = 0.0;
#pragma unroll
        for (int k = 0; k < NCOPY; ++k) {
            sum += g.st[k * 64 + tid];
            sqs += g.st[k * 64 + tid + 32];
        }
        double mean = sum / (double)n;
        double var = (sqs - sum * sum / (double)n) / (double)(n - 1);
        fm[tid] = (float)mean;
        fr[tid] = (float)(1.0 / sqrt(var));
    }
    __syncthreads();
    int t4 = (blockIdx.x * 256 + tid) * 4;
    if (t4 < n * OUTD) {
        const __half2* O = (const __half2*)g.o16;
        float2 u0 = __half22float2(O[t4 / 2]);
        float2 u1 = __half22float2(O[t4 / 2 + 1]);
        int c = t4 & 31;
        float4 r;
        r.x = (u0.x - fm[c])     * fr[c];
        r.y = (u0.y - fm[c + 1]) * fr[c + 1];
        r.z = (u1.x - fm[c + 2]) * fr[c + 2];
        r.w = (u1.y - fm[c + 3]) * fr[c + 3];
        *(float4*)&g.og[t4] = r;
    }
}

// ---------------- launch ----------------

extern "C" void kernel_launch(void* const* d_in, const int* in_sizes, int n_in,
                              void* d_out, int out_size, void* d_ws, size_t ws_size,
                              hipStream_t stream) {
    const float* x1 = (const float*)d_in[0];
    const int*   ei1 = (const int*)d_in[1];
    const float* x2 = (const float*)d_in[2];
    const int*   ei2 = (const int*)d_in[3];
    const float* W1 = (const float*)d_in[4];
    const float* b1 = (const float*)d_in[5];
    const float* W2 = (const float*)d_in[6];
    const float* b2 = (const float*)d_in[7];
    (void)b2;  // column-constant shift cancels exactly in the z-score
    (void)n_in; (void)out_size; (void)ws_size;

    int n = in_sizes[0] / IN_DIM;    // 50000
    int e = in_sizes[1] / 2;         // 800000
    float* out = (float*)d_out;
    int nb  = (n + BSZ - 1) >> BSH;  // 196 buckets (must be <= 256 for inline scans)
    int nbh = (e + EPB - 1) / EPB;   // 196 edge blocks (must be <= 256)
    int nmm = (n + 63) / 64;         // 782 matmul blocks

    char* ws = (char*)d_ws;
    size_t off = 0;
    auto alloc = [&](size_t bytes) {
        void* p = ws + off;
        off = (off + bytes + 255) & ~(size_t)255;
        return p;
    };
    int*    bh_base   = (int*)alloc((size_t)2 * nbh * nb * 4);
    int*    btot_base = (int*)alloc((size_t)2 * nb * 4);
    double* st_base   = (double*)alloc((size_t)2 * NCOPY * 64 * 8);
    _Float16* o16_base = (_Float16*)alloc((size_t)2 * n * OUTD * 2);
    _Float16* wt16     = (_Float16*)alloc((size_t)HID * IN_DIM * 2);  // W1^T fp16

    GB G[2];
    for (int g = 0; g < 2; ++g) {
        const int* ei = g ? ei2 : ei1;
        G[g].src  = ei;
        G[g].dst  = ei + e;
        G[g].x    = g ? x2 : x1;
        G[g].bh   = bh_base + (size_t)g * nbh * nb;
        G[g].btot = btot_base + (size_t)g * nb;
        G[g].st   = st_base + (size_t)g * NCOPY * 64;
        G[g].o16  = o16_base + (size_t)g * n * OUTD;
        G[g].rowptr  = (int*)alloc(((size_t)n + 1) * 4);
        G[g].csr_src = (int*)alloc((size_t)e * 4);
        G[g].dinv    = (float*)alloc((size_t)n * 4);
        G[g].og      = out + (size_t)g * n * OUTD;
        G[g].hs      = (_Float16*)alloc((size_t)n * HID * 2);  // live from p2mm on
    }
    // pairs (dead after local_csr) aliases h2 buffers (live from gather_fuse on)
    size_t pairs_bytes = (size_t)2 * e * 4;
    size_t h2_bytes    = (size_t)2 * n * OUTD * 2;
    char* uni = (char*)alloc(pairs_bytes > h2_bytes ? pairs_bytes : h2_bytes);
    G[0].pairs = (unsigned int*)uni;
    G[1].pairs = G[0].pairs + e;
    G[0].h2 = (__half*)uni;
    G[1].h2 = G[0].h2 + (size_t)n * OUTD;

    // stage 1: histogram both graphs (+1 block W1^T prep)
    k_hist<<<dim3(2 * nbh + 1), 256, 0, stream>>>(G[0], G[1], W1, wt16, e, nb, nbh);
    // stage 2: per-bucket column scans (both graphs via y)
    k_colscan<<<dim3(nb, 2), 256, 0, stream>>>(G[0], G[1], nb, nbh);
    // stage 3: partition (XCD-partitioned) + MFMA matmul fused in one launch
    int slotsP = ((nbh + 3) / 4) * 8;
    k_p2mm<<<dim3(slotsP + 2 * nmm), 256, 0, stream>>>(G[0], G[1], wt16, e, n, nb, nbh, slotsP, nmm);
    // stage 4: local CSR + prescale (XCD-partitioned)
    int slotsC = ((nb + 3) / 4) * 8;
    k_local_csr<<<dim3(slotsC), BSZ, 0, stream>>>(G[0], G[1], n, e, nb);

    // gathers, XCD-partitioned by graph (slots 0-3 -> g0, 4-7 -> g1)
    int nblkg1 = (n + 31) / 32;
    int slots1 = ((nblkg1 + 3) / 4) * 8;
    k_gather_fuse<<<dim3(slots1), 256, 0, stream>>>(G[0], G[1], b1, W2, n, nblkg1);
    int nblkg2 = (n + 63) / 64;
    int slots2 = ((nblkg2 + 3) / 4) * 8;
    k_gather2s<<<dim3(slots2), 256, 0, stream>>>(G[0], G[1], n, nblkg2);

    // z-score transform (finalize folded; st zeroed in k_colscan)
    k_transform<<<dim3((n * OUTD / 4 + 255) / 256, 2), 256, 0, stream>>>(G[0], G[1], n);
}